// Round 14
// baseline (1543.534 us; speedup 1.0000x reference)
//
#include <hip/hip_runtime.h>
#include <math.h>

#define NB 4
#define L0 8192
#define CR 32
#define CD 32
#define CS 512
#define CE 256
#define NV 256
#define OUT_T 5632
#define XSTRIDE 8192
#define NL 50
#define KCAT 1600   // 50 * 32
#define TW 64       // pair-kernel output tile width

typedef __attribute__((ext_vector_type(8))) short  short8;
typedef __attribute__((ext_vector_type(4))) float  f32x4;
typedef __attribute__((ext_vector_type(4))) float  f4;
typedef __attribute__((ext_vector_type(4))) unsigned short us4;

static __device__ __forceinline__ unsigned short f2bf(float f) {
    unsigned int u = __builtin_bit_cast(unsigned int, f);
    u = (u + 0x7FFFu + ((u >> 16) & 1u)) >> 16;
    return (unsigned short)u;
}

// ---------------- Kernel P: weight f32 -> bf16 prep ----------------
__global__ __launch_bounds__(256) void k_prep(const float* __restrict__ sw,
                                              const float* __restrict__ w1,
                                              const float* __restrict__ w2,
                                              unsigned short* __restrict__ wsb,
                                              unsigned short* __restrict__ w1b,
                                              unsigned short* __restrict__ w2b)
{
    int idx = blockIdx.x * 256 + threadIdx.x;
    if (idx < NL * CS * CD) {
        int l = idx >> 14;
        int co = (idx >> 5) & 511;
        int c = idx & 31;
        wsb[co * KCAT + l * 32 + c] = f2bf(sw[idx]);
    } else if (idx < NL * CS * CD + CE * CS) {
        int e = idx - NL * CS * CD;
        w1b[e] = f2bf(w1[e]);
    } else {
        int e = idx - NL * CS * CD - CE * CS;
        w2b[e] = f2bf(w2[e]);
    }
}

// ---------------- Kernel A: embedding + causal pre-conv (k=2) ----------------
__global__ __launch_bounds__(256) void k_pre(const int* __restrict__ tokens,
                                             const float* __restrict__ emb,
                                             const float* __restrict__ pw,
                                             float* __restrict__ x)
{
    int idx = blockIdx.x * 256 + threadIdx.x;
    int t = idx & (L0 - 1);
    int o = (idx >> 13) & 31;
    int b = idx >> 18;
    const int* tb = tokens + b * L0;
    const float* e1 = emb + tb[t] * CR;
    const float* w = pw + o * CR * 2;
    float acc = 0.f;
    if (t > 0) {
        const float* e0 = emb + tb[t - 1] * CR;
#pragma unroll
        for (int i = 0; i < CR; ++i)
            acc += w[i * 2] * e0[i] + w[i * 2 + 1] * e1[i];
    } else {
#pragma unroll
        for (int i = 0; i < CR; ++i)
            acc += w[i * 2 + 1] * e1[i];
    }
    x[(b * CR + o) * XSTRIDE + t] = acc;
}

// ---------------- Pair kernel (v2): 2 layers, TW=64, 256 thr, ~71.6 KB LDS ----------------
struct PairSmem2 {
    float X[4][32][68];    // taps: {A, A+d1, B, B+d1} of layer-1 input coords
    float Z[2][32][68];    // z for A-tile, B-tile (then reused for layer 2)
    float wfT[64][33];
    float wgT[64][33];
    float rwT[32][33];
};

static __device__ __forceinline__ void gate_tile2(
    const float (*__restrict__ X0)[68], const float (*__restrict__ X1)[68],
    float (*__restrict__ Zf)[68],
    const float (*__restrict__ wf)[33], const float (*__restrict__ wg)[33],
    int c, int j0)
{
    float af[8] = {0, 0, 0, 0, 0, 0, 0, 0};
    float ag[8] = {0, 0, 0, 0, 0, 0, 0, 0};
#pragma unroll
    for (int i = 0; i < 32; ++i) {
        float av[8], bv[8];
        *(f4*)&av[0] = *(const f4*)&X0[i][j0];
        *(f4*)&av[4] = *(const f4*)&X0[i][j0 + 4];
        *(f4*)&bv[0] = *(const f4*)&X1[i][j0];
        *(f4*)&bv[4] = *(const f4*)&X1[i][j0 + 4];
        float f0 = wf[2 * i][c], f1 = wf[2 * i + 1][c];
        float g0 = wg[2 * i][c], g1 = wg[2 * i + 1][c];
#pragma unroll
        for (int k = 0; k < 8; ++k) {
            af[k] += f0 * av[k] + f1 * bv[k];
            ag[k] += g0 * av[k] + g1 * bv[k];
        }
    }
#pragma unroll
    for (int k = 0; k < 8; ++k) {
        float e2a = __expf(2.f * af[k]);
        float th = 1.f - __fdividef(2.f, e2a + 1.f);
        float sg = __fdividef(1.f, 1.f + __expf(-ag[k]));
        Zf[c][j0 + k] = th * sg;
    }
}

// z store helper: transposed read of Z (stride 68 floats -> conflict-light),
// pack 8 channels to short8, guarded store to Zt.
static __device__ __forceinline__ void zt_store(
    const float (*__restrict__ Zf)[68], unsigned short* __restrict__ Zt,
    int b, int tl, int cq, int u, int skipO, int Tlim, int kOff)
{
    if (u >= skipO && u < Tlim) {
        short8 pk;
#pragma unroll
        for (int q = 0; q < 8; ++q)
            pk[q] = (short)f2bf(Zf[cq + q][tl]);
        unsigned short* dst =
            Zt + ((size_t)b * OUT_T + (u - skipO)) * KCAT + kOff + cq;
        *(short8*)dst = pk;
    }
}

// layer1: z1[u]=act(Wf1·x1in(u), x1in(u+d1)); x1out[u]=Wr1 z1[u]+x1in(u+d1);
//         x1in(u)=(0<=u-P1<T0)? x0[u-P1] : 0
// layer2: x2in(t)=(t<P2)?0:x1out[t-P2]; needs x1out at A=t0-P2 and B=t0+d2-P2.
__global__ __launch_bounds__(256) void k_pair(
    const float* __restrict__ x0, float* __restrict__ x_out,
    unsigned short* __restrict__ Zt,
    const float* __restrict__ fw1, const float* __restrict__ gw1,
    const float* __restrict__ rw1,
    const float* __restrict__ fw2, const float* __restrict__ gw2,
    const float* __restrict__ rw2,
    int T0, int T1, int T2, int d1, int d2, int P1, int P2,
    int skip1, int skip2, int kOff1, int kOff2)
{
    extern __shared__ char smraw[];
    PairSmem2& sm = *reinterpret_cast<PairSmem2*>(smraw);
    const int tid = threadIdx.x;
    const int b = blockIdx.y;
    const int t0 = blockIdx.x * TW;
    const int baseA = t0 - P2;
    const int baseB = t0 + d2 - P2;

    // ---- P0: stage layer-1 weights + load 4 input tiles ----
    for (int e = tid; e < 2048; e += 256) {
        int c = e >> 6, i2 = e & 63;
        sm.wfT[i2][c] = fw1[e];
        sm.wgT[i2][c] = gw1[e];
    }
    for (int e = tid; e < 1024; e += 256)
        sm.rwT[e & 31][e >> 5] = rw1[e];
    {
        int ch = tid >> 3;
        int j0 = (tid & 7) * 8;
        const float* row = x0 + ((size_t)b * CR + ch) * XSTRIDE;
        const int bases[4] = {baseA, baseA + d1, baseB, baseB + d1};
#pragma unroll
        for (int q = 0; q < 4; ++q) {
            int iu0 = bases[q] + j0 - P1;
            float v[8];
            if (iu0 >= 0 && iu0 + 7 < T0) {
#pragma unroll
                for (int k = 0; k < 8; ++k) v[k] = row[iu0 + k];
            } else {
#pragma unroll
                for (int k = 0; k < 8; ++k) {
                    int iu = iu0 + k;
                    v[k] = (iu >= 0 && iu < T0) ? row[iu] : 0.f;
                }
            }
#pragma unroll
            for (int k = 0; k < 8; ++k) sm.X[q][ch][j0 + k] = v[k];
        }
    }
    __syncthreads();

    // ---- P1: layer-1 gates for A and B tiles ----
    {
        int c = tid & 31;
        int j0 = (tid >> 5) * 8;
        gate_tile2(sm.X[0], sm.X[1], sm.Z[0], sm.wfT, sm.wgT, c, j0);
        gate_tile2(sm.X[2], sm.X[3], sm.Z[1], sm.wfT, sm.wgT, c, j0);
    }
    __syncthreads();

    // ---- P2: restage wf/wg for layer 2; layer-1 Zt stores; residuals ----
    for (int e = tid; e < 2048; e += 256) {      // wfT/wgT last read in P1
        int c = e >> 6, i2 = e & 63;
        sm.wfT[i2][c] = fw2[e];
        sm.wgT[i2][c] = gw2[e];
    }
    {
        int tl = tid >> 2;
        int cq = (tid & 3) * 8;
        zt_store(sm.Z[0], Zt, b, tl, cq, baseA + tl, skip1, T1, kOff1);
        zt_store(sm.Z[1], Zt, b, tl, cq, baseB + tl, skip1, T1, kOff1);
    }
    {
        int ch = tid >> 3;
        int j0 = (tid & 7) * 8;
        float accA[8], accB[8];
        *(f4*)&accA[0] = *(const f4*)&sm.X[1][ch][j0];
        *(f4*)&accA[4] = *(const f4*)&sm.X[1][ch][j0 + 4];
        *(f4*)&accB[0] = *(const f4*)&sm.X[3][ch][j0];
        *(f4*)&accB[4] = *(const f4*)&sm.X[3][ch][j0 + 4];
#pragma unroll
        for (int i = 0; i < 32; ++i) {
            float w = sm.rwT[i][ch];
            float za[8], zb[8];
            *(f4*)&za[0] = *(const f4*)&sm.Z[0][i][j0];
            *(f4*)&za[4] = *(const f4*)&sm.Z[0][i][j0 + 4];
            *(f4*)&zb[0] = *(const f4*)&sm.Z[1][i][j0];
            *(f4*)&zb[4] = *(const f4*)&sm.Z[1][i][j0 + 4];
#pragma unroll
            for (int k = 0; k < 8; ++k) {
                accA[k] += w * za[k];
                accB[k] += w * zb[k];
            }
        }
#pragma unroll
        for (int k = 0; k < 8; ++k) {
            // x2in(t) = 0 for t < P2 (layer-2 front pad), else x1out[t-P2]
            sm.X[0][ch][j0 + k] = (t0 + j0 + k >= P2) ? accA[k] : 0.f;
            sm.X[2][ch][j0 + k] = accB[k];
        }
    }
    __syncthreads();

    // ---- P3: layer-2 gate; restage rw2 ----
    for (int e = tid; e < 1024; e += 256)        // rwT last read in P2
        sm.rwT[e & 31][e >> 5] = rw2[e];
    {
        int c = tid & 31;
        int j0 = (tid >> 5) * 8;
        gate_tile2(sm.X[0], sm.X[2], sm.Z[0], sm.wfT, sm.wgT, c, j0);
    }
    __syncthreads();

    // ---- P4: layer-2 Zt store + x2out ----
    {
        int tl = tid >> 2;
        int cq = (tid & 3) * 8;
        zt_store(sm.Z[0], Zt, b, tl, cq, t0 + tl, skip2, T2, kOff2);
    }
    {
        int ch = tid >> 3;
        int j0 = (tid & 7) * 8;
        float acc[8];
        *(f4*)&acc[0] = *(const f4*)&sm.X[2][ch][j0];
        *(f4*)&acc[4] = *(const f4*)&sm.X[2][ch][j0 + 4];
#pragma unroll
        for (int i = 0; i < 32; ++i) {
            float w = sm.rwT[i][ch];
            float zv[8];
            *(f4*)&zv[0] = *(const f4*)&sm.Z[0][i][j0];
            *(f4*)&zv[4] = *(const f4*)&sm.Z[0][i][j0 + 4];
#pragma unroll
            for (int k = 0; k < 8; ++k)
                acc[k] += w * zv[k];
        }
        float* orow = x_out + ((size_t)b * CR + ch) * XSTRIDE;
#pragma unroll
        for (int k = 0; k < 8; ++k) {
            int t = t0 + j0 + k;
            if (t < T2) orow[t] = acc[k];
        }
    }
}

// ---------------- MFMA GEMM: C[b] = A * B[b]^T(+bias)(+relu), 128x128 tile ----------------
template <int MODE>
__global__ __launch_bounds__(256) void k_gemm(
    const unsigned short* __restrict__ A,
    const unsigned short* __restrict__ B,
    const float* __restrict__ bias,
    void* __restrict__ Cout, int M, int K)
{
    __shared__ unsigned short Asm[128][72];
    __shared__ unsigned short Bsm[128][72];
    const int tid = threadIdx.x;
    const int n0 = blockIdx.x * 128;
    const int m0 = blockIdx.y * 128;
    const int b = blockIdx.z;
    const unsigned short* Bb = B + (size_t)b * OUT_T * K;
    const int lane = tid & 63;
    const int wm = tid >> 6;
    f32x4 acc[2][8];
#pragma unroll
    for (int fm = 0; fm < 2; ++fm)
#pragma unroll
        for (int fn = 0; fn < 8; ++fn)
            acc[fm][fn] = (f32x4){0.f, 0.f, 0.f, 0.f};

    for (int kb = 0; kb < K; kb += 64) {
        __syncthreads();
#pragma unroll
        for (int it = 0; it < 4; ++it) {
            int lin = tid + it * 256;
            int row = lin >> 3, c8 = (lin & 7) * 8;
            *(short8*)&Asm[row][c8] =
                *(const short8*)&A[(size_t)(m0 + row) * K + kb + c8];
        }
#pragma unroll
        for (int it = 0; it < 4; ++it) {
            int lin = tid + it * 256;
            int row = lin >> 3, c8 = (lin & 7) * 8;
            *(short8*)&Bsm[row][c8] =
                *(const short8*)&Bb[(size_t)(n0 + row) * K + kb + c8];
        }
        __syncthreads();
#pragma unroll
        for (int kk = 0; kk < 2; ++kk) {
            short8 a[2], bb[8];
#pragma unroll
            for (int fm = 0; fm < 2; ++fm)
                a[fm] = *(const short8*)&Asm[wm * 32 + fm * 16 + (lane & 15)]
                                           [kk * 32 + (lane >> 4) * 8];
#pragma unroll
            for (int fn = 0; fn < 8; ++fn)
                bb[fn] = *(const short8*)&Bsm[fn * 16 + (lane & 15)]
                                            [kk * 32 + (lane >> 4) * 8];
#pragma unroll
            for (int fm = 0; fm < 2; ++fm)
#pragma unroll
                for (int fn = 0; fn < 8; ++fn)
                    acc[fm][fn] = __builtin_amdgcn_mfma_f32_16x16x32_bf16(
                        a[fm], bb[fn], acc[fm][fn], 0, 0, 0);
        }
    }
#pragma unroll
    for (int fm = 0; fm < 2; ++fm) {
        int mb = m0 + wm * 32 + fm * 16 + (lane >> 4) * 4;
#pragma unroll
        for (int fn = 0; fn < 8; ++fn) {
            int n = n0 + fn * 16 + (lane & 15);
            float v[4];
#pragma unroll
            for (int r = 0; r < 4; ++r) {
                v[r] = acc[fm][fn][r];
                if (MODE >= 1) v[r] += bias[mb + r];
                if (MODE <= 1) v[r] = v[r] > 0.f ? v[r] : 0.f;
            }
            if (MODE == 2) {
                float* o = (float*)Cout;
#pragma unroll
                for (int r = 0; r < 4; ++r)
                    o[((size_t)b * NV + mb + r) * OUT_T + n] = v[r];
            } else {
                unsigned short* o = (unsigned short*)Cout;
                us4 pk;
#pragma unroll
                for (int r = 0; r < 4; ++r) pk[r] = f2bf(v[r]);
                *(us4*)&o[((size_t)b * OUT_T + n) * M + mb] = pk;
            }
        }
    }
}

extern "C" void kernel_launch(void* const* d_in, const int* in_sizes, int n_in,
                              void* d_out, int out_size, void* d_ws, size_t ws_size,
                              hipStream_t stream)
{
    const int*   tokens  = (const int*)d_in[0];
    const float* emb     = (const float*)d_in[1];
    const float* pre_w   = (const float*)d_in[2];
    const float* filt_w  = (const float*)d_in[3];
    const float* gate_w  = (const float*)d_in[4];
    const float* res_w   = (const float*)d_in[5];
    const float* skip_w  = (const float*)d_in[6];
    const float* post_w1 = (const float*)d_in[7];
    const float* post_b1 = (const float*)d_in[8];
    const float* post_w2 = (const float*)d_in[9];
    const float* post_b2 = (const float*)d_in[10];
    float* out = (float*)d_out;

    char* ws = (char*)d_ws;
    float* xA = (float*)ws;                 ws += (size_t)NB * CR * XSTRIDE * 4;
    float* xB = (float*)ws;                 ws += (size_t)NB * CR * XSTRIDE * 4;
    unsigned short* Zt    = (unsigned short*)ws; ws += (size_t)NB * OUT_T * KCAT * 2;
    unsigned short* skipT = (unsigned short*)ws; ws += (size_t)NB * OUT_T * CS * 2;
    unsigned short* h1T   = (unsigned short*)ws; ws += (size_t)NB * OUT_T * CE * 2;
    unsigned short* wsb   = (unsigned short*)ws; ws += (size_t)CS * KCAT * 2;
    unsigned short* w1b   = (unsigned short*)ws; ws += (size_t)CE * CS * 2;
    unsigned short* w2b   = (unsigned short*)ws; ws += (size_t)NV * CE * 2;

    k_prep<<<3968, 256, 0, stream>>>(skip_w, post_w1, post_w2, wsb, w1b, w2b);
    k_pre<<<(NB * CR * L0) / 256, 256, 0, stream>>>(tokens, emb, pre_w, xA);

    // static layer schedule (mirrors reference dilate() padding)
    int dArr[NL], pArr[NL], tArr[NL];
    {
        int T = L0, init = 1, li = 0;
        for (int blk = 0; blk < 5; ++blk) {
            int nw = 1;
            for (int j = 0; j < 10; ++j) {
                int d = nw, P = 0;
                if (d > init) {
                    int r = d / init;
                    int l = T / init;
                    int nl = ((l + r - 1) / r) * r;
                    P = (nl - l) * init;
                }
                int T_out = T + P - d;
                dArr[li] = d; pArr[li] = P; tArr[li] = T_out;
                T = T_out; init = d; nw <<= 1; ++li;
            }
        }
    }

    // 25 pair kernels; dilation pairs (1,2),(4,8),(16,32),(64,128),(256,512)
    float* xin = xA;
    float* xout = xB;
    for (int p = 0; p < 25; ++p) {
        int l1 = 2 * p, l2 = 2 * p + 1;
        int T0 = (l1 == 0) ? L0 : tArr[l1 - 1];
        int T1 = tArr[l1], T2 = tArr[l2];
        int ntiles = (T2 + TW - 1) / TW;
        dim3 grid(ntiles, NB);
        k_pair<<<grid, 256, sizeof(PairSmem2), stream>>>(
            xin, xout, Zt,
            filt_w + (size_t)l1 * CD * CR * 2,
            gate_w + (size_t)l1 * CD * CR * 2,
            res_w + (size_t)l1 * CR * CD,
            filt_w + (size_t)l2 * CD * CR * 2,
            gate_w + (size_t)l2 * CD * CR * 2,
            res_w + (size_t)l2 * CR * CD,
            T0, T1, T2, dArr[l1], dArr[l2], pArr[l1], pArr[l2],
            T1 - OUT_T, T2 - OUT_T, l1 * 32, l2 * 32);
        float* tmp = xin; xin = xout; xout = tmp;
    }

    dim3 gs(OUT_T / 128, CS / 128, NB);
    k_gemm<0><<<gs, 256, 0, stream>>>(wsb, Zt, nullptr, skipT, CS, KCAT);
    dim3 g1(OUT_T / 128, CE / 128, NB);
    k_gemm<1><<<g1, 256, 0, stream>>>(w1b, skipT, post_b1, h1T, CE, CS);
    dim3 g2(OUT_T / 128, NV / 128, NB);
    k_gemm<2><<<g2, 256, 0, stream>>>(w2b, h1T, post_b2, out, NV, CE);
}